// Round 7
// baseline (13236.053 us; speedup 1.0000x reference)
//
#include <hip/hip_runtime.h>
#include <math.h>

#define B_    4096
#define A_    6
#define V_    1024
#define L_    32
#define DIN_  64
#define DOUT_ 64
#define H_    512
#define ROWS  16
#define NT    1024
#define AD    384          // A_*DIN_
#define GT_N  128          // gate N-tiles (2048/16)
#define GT_K  18           // 16 h-Ktiles + 2 emb-Ktiles
#define LG_N  64           // logit N-tiles (1024/16)
#define LG_K  16           // 512/32

typedef __attribute__((ext_vector_type(8))) short short8;   // 8 bf16 (guide §3)
typedef __attribute__((ext_vector_type(4))) float f32x4;

static constexpr size_t GW_HALF = (size_t)GT_N * GT_K * 512; // ushort per split
static constexpr size_t LW_HALF = (size_t)LG_N * LG_K * 512;

// ---- bf16 helpers (manual RNE; avoids __bf16 type portability issues) ----
__device__ __forceinline__ unsigned short bfhi(float v) {
  union { float f; unsigned u; } a; a.f = v;
  unsigned r = a.u + 0x7FFFu + ((a.u >> 16) & 1u);
  return (unsigned short)(r >> 16);
}
__device__ __forceinline__ float bf2f(unsigned short s) {
  union { unsigned u; float f; } a; a.u = (unsigned)s << 16;
  return a.f;
}
__device__ __forceinline__ void bfsplit(float v, unsigned short& hi, unsigned short& lo) {
  hi = bfhi(v);
  lo = bfhi(v - bf2f(hi));
}

// LDS swizzles (index in ushort units; rows stay within row; 8-aligned chunks)
__device__ __forceinline__ int swzA(int m, int k) { return m * 512 + (k ^ (m << 3)); }
__device__ __forceinline__ int swzE(int m, int k) { return m * 64 + (k ^ ((m & 7) << 3)); }

// ---- pack gates W_ih[2048][64], W_hh[2048][512] -> B-fragment order ----
// k-slot convention: kappa(l,e) = (l>>4)*8 + e  (MUST match A-frag fill)
__global__ void pack_gw(const float* __restrict__ W_ih, const float* __restrict__ W_hh,
                        unsigned short* __restrict__ WgB) {
  int idx = blockIdx.x * 256 + threadIdx.x;        // < GT_N*GT_K*64
  int lane = idx & 63;
  int kt   = (idx >> 6) % GT_K;
  int tn   = idx / (GT_K * 64);
  int l15 = lane & 15, lg = lane >> 4;
  int g = tn >> 5, jblk = tn & 31;
  int gcol = g * 512 + jblk * 16 + l15;            // B col n
  size_t bh = ((size_t)tn * GT_K + kt) * 512 + (size_t)lane * 8;
  #pragma unroll
  for (int e = 0; e < 8; e++) {
    int kk = lg * 8 + e;
    float v = (kt < 16) ? W_hh[(size_t)gcol * H_ + kt * 32 + kk]
                        : W_ih[(size_t)gcol * DOUT_ + (kt - 16) * 32 + kk];
    unsigned short hi, lo; bfsplit(v, hi, lo);
    WgB[bh + e]           = hi;
    WgB[GW_HALF + bh + e] = lo;
  }
}

// ---- pack Wo[512][1024] -> B-fragment order ----
__global__ void pack_lw(const float* __restrict__ Wo, unsigned short* __restrict__ WoB) {
  int idx = blockIdx.x * 256 + threadIdx.x;        // < LG_N*LG_K*64
  int lane = idx & 63;
  int kt = (idx >> 6) % LG_K;
  int vb = idx / (LG_K * 64);
  int l15 = lane & 15, lg = lane >> 4;
  int n = vb * 16 + l15;
  size_t bh = ((size_t)vb * LG_K + kt) * 512 + (size_t)lane * 8;
  #pragma unroll
  for (int e = 0; e < 8; e++) {
    int k = kt * 32 + lg * 8 + e;
    unsigned short hi, lo; bfsplit(Wo[(size_t)k * V_ + n], hi, lo);
    WoB[bh + e]           = hi;
    WoB[LW_HALF + bh + e] = lo;
  }
}

#define MFMA(A, Bv, C) __builtin_amdgcn_mfma_f32_16x16x32_bf16((A), (Bv), (C), 0, 0, 0)

// ---------------- fused 32-step LSTM decoder, bf16x3 MFMA ----------------
// Block = 16 batch rows, 16 waves. Gates: wave w owns (g=0..3, jb=0..1) tiles
// tn = g*32 + 2w+jb. Logits: wave w owns vblk 4w..4w+3. C-frag (verified m89):
// row = (lane>>4)*4+reg, col = lane&15.
__launch_bounds__(NT)
__global__ void lstm_mfma(
    const int*   __restrict__ x,
    const float* __restrict__ input_emb,
    const float* __restrict__ output_emb,
    const float* __restrict__ Wi,          // [AD][H] raw fp32 (prologue only)
    const float* __restrict__ bi,
    const float* __restrict__ b_ih,
    const float* __restrict__ b_hh,
    const float* __restrict__ bo,
    const float* __restrict__ sos,
    const unsigned short* __restrict__ WgB, // packed gate weights hi|lo
    const unsigned short* __restrict__ WoB, // packed logit weights hi|lo
    float* __restrict__ out)
{
  __shared__ __align__(16) unsigned short shA_hi[ROWS * H_];    // 16 KB
  __shared__ __align__(16) unsigned short shA_lo[ROWS * H_];    // 16 KB
  __shared__ __align__(16) unsigned short seA_hi[ROWS * DOUT_]; // 2 KB
  __shared__ __align__(16) unsigned short seA_lo[ROWS * DOUT_]; // 2 KB
  __shared__ __align__(16) float sbuf[ROWS * AD];               // 24 KB (prologue e / cands)

  const int t    = threadIdx.x;
  const int r0   = blockIdx.x * ROWS;
  const int lane = t & 63, w = t >> 6;
  const int l15  = lane & 15, lg = lane >> 4;

  float* out_seq    = out;
  float* out_logits = out + (size_t)B_ * L_;

  // ---- prologue: gather e; semb = sos ----
  for (int idx = t; idx < ROWS * AD; idx += NT) {
    int r = idx / AD, rem = idx - r * AD;
    int a = rem >> 6, d = rem & 63;
    sbuf[idx] = input_emb[x[(r0 + r) * A_ + a] * DIN_ + d];
  }
  {
    int r = t >> 6, d = t & 63;
    unsigned short hi, lo; bfsplit(sos[d], hi, lo);
    int si = swzE(r, d);
    seA_hi[si] = hi; seA_lo[si] = lo;
  }
  __syncthreads();

  // ---- h0 = e @ Wi + bi (fp32 vector path, one-time) ----
  {
    int j = t & 511, rb = (t >> 9) * 8;
    float acc[8];
    #pragma unroll
    for (int r = 0; r < 8; r++) acc[r] = 0.f;
    for (int k = 0; k < AD; k++) {
      float wv = Wi[(size_t)k * H_ + j];
      #pragma unroll
      for (int r = 0; r < 8; r++)
        acc[r] = fmaf(sbuf[(rb + r) * AD + k], wv, acc[r]);
    }
    float bj = bi[j];
    #pragma unroll
    for (int r = 0; r < 8; r++) {
      unsigned short hi, lo; bfsplit(acc[r] + bj, hi, lo);
      int si = swzA(rb + r, j);
      shA_hi[si] = hi; shA_lo[si] = lo;
    }
  }
  __syncthreads();

  // ---- persistent per-lane state ----
  float creg[2][4];
  #pragma unroll
  for (int jb = 0; jb < 2; jb++)
    #pragma unroll
    for (int reg = 0; reg < 4; reg++) creg[jb][reg] = 0.f;

  float biasg[8];
  int   goff[8];
  #pragma unroll
  for (int tt = 0; tt < 8; tt++) {
    int g = tt >> 1, jb = tt & 1;
    int tn = g * 32 + 2 * w + jb;
    int gcol = g * 512 + (2 * w + jb) * 16 + l15;
    biasg[tt] = b_ih[gcol] + b_hh[gcol];
    goff[tt]  = tn * GT_K * 512 + lane * 8;
  }
  float biasl[4];
  int   loff[4];
  #pragma unroll
  for (int tt = 0; tt < 4; tt++) {
    biasl[tt] = bo[(4 * w + tt) * 16 + l15];
    loff[tt]  = (4 * w + tt) * LG_K * 512 + lane * 8;
  }

  float* cand_v = sbuf;
  int*   cand_i = (int*)(sbuf + 256);

  for (int step = 0; step < L_; step++) {
    // ================= gates =================
    f32x4 ag[8];
    #pragma unroll
    for (int tt = 0; tt < 8; tt++) {
      float b = biasg[tt];
      ag[tt] = (f32x4){b, b, b, b};
    }
    for (int kt = 0; kt < 16; kt++) {            // h part (K=512)
      int ai = swzA(l15, kt * 32 + lg * 8);
      short8 Ah = *(const short8*)&shA_hi[ai];
      short8 Al = *(const short8*)&shA_lo[ai];
      #pragma unroll
      for (int tt = 0; tt < 8; tt++) {
        const unsigned short* p = WgB + (size_t)goff[tt] + kt * 512;
        short8 Bh = *(const short8*)p;
        short8 Bl = *(const short8*)(p + GW_HALF);
        ag[tt] = MFMA(Ah, Bh, ag[tt]);
        ag[tt] = MFMA(Al, Bh, ag[tt]);
        ag[tt] = MFMA(Ah, Bl, ag[tt]);
      }
    }
    #pragma unroll
    for (int kt2 = 0; kt2 < 2; kt2++) {          // emb part (K=64)
      int ai = swzE(l15, kt2 * 32 + lg * 8);
      short8 Ah = *(const short8*)&seA_hi[ai];
      short8 Al = *(const short8*)&seA_lo[ai];
      #pragma unroll
      for (int tt = 0; tt < 8; tt++) {
        const unsigned short* p = WgB + (size_t)goff[tt] + (16 + kt2) * 512;
        short8 Bh = *(const short8*)p;
        short8 Bl = *(const short8*)(p + GW_HALF);
        ag[tt] = MFMA(Ah, Bh, ag[tt]);
        ag[tt] = MFMA(Al, Bh, ag[tt]);
        ag[tt] = MFMA(Ah, Bl, ag[tt]);
      }
    }

    // ---- cell update: lane holds rows lg*4+reg, cols (2w+jb)*16+l15 ----
    unsigned short hh[8], hl[8];
    #pragma unroll
    for (int jb = 0; jb < 2; jb++)
      #pragma unroll
      for (int reg = 0; reg < 4; reg++) {
        float iv = 1.f / (1.f + expf(-ag[0 + jb][reg]));
        float fv = 1.f / (1.f + expf(-ag[2 + jb][reg]));
        float gv = tanhf(ag[4 + jb][reg]);
        float ov = 1.f / (1.f + expf(-ag[6 + jb][reg]));
        float cn = fv * creg[jb][reg] + iv * gv;
        creg[jb][reg] = cn;
        bfsplit(ov * tanhf(cn), hh[jb * 4 + reg], hl[jb * 4 + reg]);
      }
    __syncthreads();                 // (a) all waves done reading old shA
    #pragma unroll
    for (int jb = 0; jb < 2; jb++)
      #pragma unroll
      for (int reg = 0; reg < 4; reg++) {
        int m = lg * 4 + reg, j = (2 * w + jb) * 16 + l15;
        int si = swzA(m, j);
        shA_hi[si] = hh[jb * 4 + reg];
        shA_lo[si] = hl[jb * 4 + reg];
      }
    __syncthreads();                 // (b) new h visible

    // ================= logits =================
    f32x4 al[4];
    #pragma unroll
    for (int tt = 0; tt < 4; tt++) {
      float b = biasl[tt];
      al[tt] = (f32x4){b, b, b, b};
    }
    for (int kt = 0; kt < 16; kt++) {
      int ai = swzA(l15, kt * 32 + lg * 8);
      short8 Ah = *(const short8*)&shA_hi[ai];
      short8 Al = *(const short8*)&shA_lo[ai];
      #pragma unroll
      for (int tt = 0; tt < 4; tt++) {
        const unsigned short* p = WoB + (size_t)loff[tt] + kt * 512;
        short8 Bh = *(const short8*)p;
        short8 Bl = *(const short8*)(p + LW_HALF);
        al[tt] = MFMA(Ah, Bh, al[tt]);
        al[tt] = MFMA(Al, Bh, al[tt]);
        al[tt] = MFMA(Ah, Bl, al[tt]);
      }
    }
    // stores (never re-read -> nontemporal)
    #pragma unroll
    for (int tt = 0; tt < 4; tt++) {
      int v = (4 * w + tt) * 16 + l15;
      #pragma unroll
      for (int reg = 0; reg < 4; reg++) {
        int m = lg * 4 + reg;
        __builtin_nontemporal_store(
            al[tt][reg], &out_logits[((size_t)(r0 + m) * L_ + step) * V_ + v]);
      }
    }
    // argmax (numpy first-index tiebreak); reduce over 16-lane row-group
    #pragma unroll
    for (int reg = 0; reg < 4; reg++) {
      float bv = al[0][reg];
      int   bx = 4 * w * 16 + l15;
      #pragma unroll
      for (int tt = 1; tt < 4; tt++) {
        float vv = al[tt][reg];
        if (vv > bv) { bv = vv; bx = (4 * w + tt) * 16 + l15; }
      }
      #pragma unroll
      for (int off = 1; off <= 8; off <<= 1) {
        float ov = __shfl_xor(bv, off);
        int   ox = __shfl_xor(bx, off);
        if (ov > bv || (ov == bv && ox < bx)) { bv = ov; bx = ox; }
      }
      if (l15 == 0) {
        int m = lg * 4 + reg;
        cand_v[m * 16 + w] = bv;
        cand_i[m * 16 + w] = bx;
      }
    }
    __syncthreads();                 // (c)
    // winner scan + emb feedback (ascending wave = ascending vocab cols)
    {
      int r = t >> 6, d = t & 63;
      float bv = cand_v[r * 16];
      int   bx = cand_i[r * 16];
      #pragma unroll
      for (int c = 1; c < 16; c++) {
        float ov = cand_v[r * 16 + c];
        int   ox = cand_i[r * 16 + c];
        if (ov > bv || (ov == bv && ox < bx)) { bv = ov; bx = ox; }
      }
      if (d == 0)
        out_seq[(size_t)(r0 + r) * L_ + step] = (float)bx;
      unsigned short hi, lo; bfsplit(output_emb[(size_t)bx * DOUT_ + d], hi, lo);
      int si = swzE(r, d);
      seA_hi[si] = hi; seA_lo[si] = lo;
    }
    __syncthreads();                 // (d)
  }
}

// ---------------- fp32 fallback (ws too small; never expected to run) ----------------
__launch_bounds__(NT)
__global__ void lstm_fb(
    const int* __restrict__ x, const float* __restrict__ input_emb,
    const float* __restrict__ output_emb, const float* __restrict__ Wi,
    const float* __restrict__ bi, const float* __restrict__ W_ih,
    const float* __restrict__ W_hh, const float* __restrict__ b_ih,
    const float* __restrict__ b_hh, const float* __restrict__ Wo,
    const float* __restrict__ bo, const float* __restrict__ sos,
    float* __restrict__ out)
{
  __shared__ __align__(16) float sh[ROWS * H_];
  __shared__ __align__(16) float semb[ROWS * DOUT_];
  __shared__ __align__(16) float sbuf[ROWS * AD];

  const int t = threadIdx.x, r0 = blockIdx.x * ROWS;
  const int j = t & 511, rbase = (t >> 9) * 8, wv = t >> 6;
  float* out_seq = out;
  float* out_logits = out + (size_t)B_ * L_;

  for (int idx = t; idx < ROWS * AD; idx += NT) {
    int r = idx / AD, rem = idx - r * AD;
    sbuf[idx] = input_emb[x[(r0 + r) * A_ + (rem >> 6)] * DIN_ + (rem & 63)];
  }
  for (int idx = t; idx < ROWS * DOUT_; idx += NT) semb[idx] = sos[idx & 63];
  __syncthreads();
  {
    float acc[8];
    #pragma unroll
    for (int r = 0; r < 8; r++) acc[r] = 0.f;
    for (int k = 0; k < AD; k++) {
      float wv2 = Wi[(size_t)k * H_ + j];
      #pragma unroll
      for (int r = 0; r < 8; r++) acc[r] = fmaf(sbuf[(rbase + r) * AD + k], wv2, acc[r]);
    }
    #pragma unroll
    for (int r = 0; r < 8; r++) sh[(rbase + r) * H_ + j] = acc[r] + bi[j];
  }
  __syncthreads();

  float creg[8];
  #pragma unroll
  for (int r = 0; r < 8; r++) creg[r] = 0.f;
  const float bii = b_ih[j] + b_hh[j];
  const float bff = b_ih[j + 512] + b_hh[j + 512];
  const float bgg = b_ih[j + 1024] + b_hh[j + 1024];
  const float boo = b_ih[j + 1536] + b_hh[j + 1536];
  const float bov = bo[t];
  float* cand_v = sbuf;
  int*   cand_i = (int*)(sbuf + 256);

  for (int step = 0; step < L_; step++) {
    float ai[8], af[8], ag2[8], ao[8];
    #pragma unroll
    for (int r = 0; r < 8; r++) { ai[r] = bii; af[r] = bff; ag2[r] = bgg; ao[r] = boo; }
    for (int k = 0; k < DOUT_; k++) {
      float w0 = W_ih[(size_t)j * DOUT_ + k], w1 = W_ih[(size_t)(j + 512) * DOUT_ + k];
      float w2 = W_ih[(size_t)(j + 1024) * DOUT_ + k], w3 = W_ih[(size_t)(j + 1536) * DOUT_ + k];
      #pragma unroll
      for (int r = 0; r < 8; r++) {
        float e = semb[(rbase + r) * DOUT_ + k];
        ai[r] = fmaf(e, w0, ai[r]); af[r] = fmaf(e, w1, af[r]);
        ag2[r] = fmaf(e, w2, ag2[r]); ao[r] = fmaf(e, w3, ao[r]);
      }
    }
    for (int k = 0; k < H_; k++) {
      float w0 = W_hh[(size_t)j * H_ + k], w1 = W_hh[(size_t)(j + 512) * H_ + k];
      float w2 = W_hh[(size_t)(j + 1024) * H_ + k], w3 = W_hh[(size_t)(j + 1536) * H_ + k];
      #pragma unroll
      for (int r = 0; r < 8; r++) {
        float hv = sh[(rbase + r) * H_ + k];
        ai[r] = fmaf(hv, w0, ai[r]); af[r] = fmaf(hv, w1, af[r]);
        ag2[r] = fmaf(hv, w2, ag2[r]); ao[r] = fmaf(hv, w3, ao[r]);
      }
    }
    float hn[8];
    #pragma unroll
    for (int r = 0; r < 8; r++) {
      float iv = 1.f / (1.f + expf(-ai[r]));
      float fv = 1.f / (1.f + expf(-af[r]));
      float gv = tanhf(ag2[r]);
      float ov = 1.f / (1.f + expf(-ao[r]));
      float cn = fv * creg[r] + iv * gv;
      creg[r] = cn;
      hn[r] = ov * tanhf(cn);
    }
    __syncthreads();
    #pragma unroll
    for (int r = 0; r < 8; r++) sh[(rbase + r) * H_ + j] = hn[r];
    __syncthreads();

    float lacc[16];
    #pragma unroll
    for (int r = 0; r < 16; r++) lacc[r] = bov;
    for (int k = 0; k < H_; k++) {
      float wv2 = Wo[(size_t)k * V_ + t];
      #pragma unroll
      for (int r = 0; r < 16; r++) lacc[r] = fmaf(sh[r * H_ + k], wv2, lacc[r]);
    }
    #pragma unroll
    for (int r = 0; r < 16; r++)
      out_logits[((size_t)(r0 + r) * L_ + step) * V_ + t] = lacc[r];
    #pragma unroll
    for (int r = 0; r < 16; r++) {
      float bv = lacc[r]; int bx = t;
      #pragma unroll
      for (int off = 32; off; off >>= 1) {
        float ov = __shfl_xor(bv, off);
        int ox = __shfl_xor(bx, off);
        if (ov > bv || (ov == bv && ox < bx)) { bv = ov; bx = ox; }
      }
      if ((t & 63) == 0) { cand_v[r * 16 + wv] = bv; cand_i[r * 16 + wv] = bx; }
    }
    __syncthreads();
    {
      int r = t >> 6, d = t & 63;
      float bv = cand_v[r * 16]; int bx = cand_i[r * 16];
      #pragma unroll
      for (int c = 1; c < 16; c++) {
        float ov = cand_v[r * 16 + c]; int ox = cand_i[r * 16 + c];
        if (ov > bv || (ov == bv && ox < bx)) { bv = ov; bx = ox; }
      }
      if (d == 0) out_seq[(size_t)(r0 + r) * L_ + step] = (float)bx;
      semb[r * DOUT_ + d] = output_emb[(size_t)bx * DOUT_ + d];
    }
    __syncthreads();
  }
}

extern "C" void kernel_launch(void* const* d_in, const int* in_sizes, int n_in,
                              void* d_out, int out_size, void* d_ws, size_t ws_size,
                              hipStream_t stream) {
  const int*   x          = (const int*)  d_in[0];
  const float* input_emb  = (const float*)d_in[1];
  const float* output_emb = (const float*)d_in[2];
  const float* Wi         = (const float*)d_in[3];
  const float* bi         = (const float*)d_in[4];
  const float* W_ih       = (const float*)d_in[5];
  const float* W_hh       = (const float*)d_in[6];
  const float* b_ih       = (const float*)d_in[7];
  const float* b_hh       = (const float*)d_in[8];
  const float* Wo         = (const float*)d_in[9];
  const float* bo         = (const float*)d_in[10];
  const float* sos        = (const float*)d_in[11];
  float* outp = (float*)d_out;

  const size_t ws_need = (2 * GW_HALF + 2 * LW_HALF) * sizeof(unsigned short); // ~6.8 MB

  if (ws_size >= ws_need) {
    unsigned short* WgB = (unsigned short*)d_ws;
    unsigned short* WoB = WgB + 2 * GW_HALF;
    pack_gw<<<(GT_N * GT_K * 64) / 256, 256, 0, stream>>>(W_ih, W_hh, WgB);
    pack_lw<<<(LG_N * LG_K * 64) / 256, 256, 0, stream>>>(Wo, WoB);
    lstm_mfma<<<B_ / ROWS, NT, 0, stream>>>(
        x, input_emb, output_emb, Wi, bi, b_ih, b_hh, bo, sos, WgB, WoB, outp);
  } else {
    lstm_fb<<<B_ / ROWS, NT, 0, stream>>>(
        x, input_emb, output_emb, Wi, bi, W_ih, W_hh, b_ih, b_hh, Wo, bo, sos, outp);
  }
}